// Round 1
// baseline (161.464 us; speedup 1.0000x reference)
//
#include <hip/hip_runtime.h>
#include <hip/hip_bf16.h>

#define BB 8
#define NN 2048
#define DD 256

typedef _Float16 half8 __attribute__((ext_vector_type(8)));
typedef float f32x4 __attribute__((ext_vector_type(4)));

__device__ __forceinline__ half8 cvt8(const float* __restrict__ p) {
    f32x4 a = *(const f32x4*)p;
    f32x4 b = *(const f32x4*)(p + 4);
    half8 h;
    h[0] = (_Float16)a[0]; h[1] = (_Float16)a[1];
    h[2] = (_Float16)a[2]; h[3] = (_Float16)a[3];
    h[4] = (_Float16)b[0]; h[5] = (_Float16)b[1];
    h[6] = (_Float16)b[2]; h[7] = (_Float16)b[3];
    return h;
}

// ---------------- Kernel A: qh = x@Wq^T, kh = x@Wk^T (fp16 out) ----------------
// 4 waves/block, each wave owns 16 token-rows; loop over 16 output-col tiles,
// staging Wq/Wk row-tiles (fp32->fp16) in LDS shared by the 4 waves.
__global__ void __launch_bounds__(256)
qk_proj(const float* __restrict__ x, const float* __restrict__ Wq,
        const float* __restrict__ Wk, _Float16* __restrict__ qh,
        _Float16* __restrict__ kh) {
    __shared__ __align__(16) _Float16 Wql[16][264];  // pad: 528B row stride
    __shared__ __align__(16) _Float16 Wkl[16][264];
    const int tid = threadIdx.x;
    const int wave = tid >> 6, lane = tid & 63;
    const int g = lane >> 4, l16 = lane & 15;
    const size_t r0 = ((size_t)blockIdx.x * 4 + wave) * 16;  // flat [B*N) row

    // A-fragments of x (fp32 -> fp16), kept in regs for all 16 col-tiles
    half8 xa[8];
#pragma unroll
    for (int c = 0; c < 8; ++c)
        xa[c] = cvt8(x + (r0 + l16) * DD + c * 32 + g * 8);

    for (int t = 0; t < 16; ++t) {
        __syncthreads();
        {   // stage Wq/Wk rows [t*16, t*16+16) as fp16
            const int sel = tid >> 7;          // 0: Wq, 1: Wk
            const int tt  = tid & 127;
            const int row = tt >> 3;           // 0..15
            const int col = (tt & 7) * 32;     // 0..224
            const float* src = (sel ? Wk : Wq) + (size_t)(t * 16 + row) * DD + col;
            _Float16* dst = sel ? &Wkl[row][col] : &Wql[row][col];
#pragma unroll
            for (int j = 0; j < 4; ++j)
                *(half8*)(dst + j * 8) = cvt8(src + j * 8);
        }
        __syncthreads();
        f32x4 aq = {0.f, 0.f, 0.f, 0.f}, ak = {0.f, 0.f, 0.f, 0.f};
#pragma unroll
        for (int c = 0; c < 8; ++c) {
            half8 bq = *(const half8*)&Wql[l16][c * 32 + g * 8];
            half8 bk = *(const half8*)&Wkl[l16][c * 32 + g * 8];
            aq = __builtin_amdgcn_mfma_f32_16x16x32_f16(xa[c], bq, aq, 0, 0, 0);
            ak = __builtin_amdgcn_mfma_f32_16x16x32_f16(xa[c], bk, ak, 0, 0, 0);
        }
#pragma unroll
        for (int r = 0; r < 4; ++r) {   // D: col=lane&15, row=(lane>>4)*4+r
            size_t row = r0 + g * 4 + r;
            qh[row * DD + t * 16 + l16] = (_Float16)aq[r];
            kh[row * DD + t * 16 + l16] = (_Float16)ak[r];
        }
    }
}

// ---------------- Kernel B: xT[b][d][n] = (fp16) x[b][n][d] ----------------
__global__ void __launch_bounds__(256)
x_transpose(const float* __restrict__ x, _Float16* __restrict__ xT) {
    __shared__ _Float16 tl[32][33];
    const int b = blockIdx.z;
    const int n0 = blockIdx.y * 32, d0 = blockIdx.x * 32;
    const int c = threadIdx.x & 31, rq = threadIdx.x >> 5;
#pragma unroll
    for (int i = 0; i < 4; ++i) {
        int row = rq + i * 8;
        tl[row][c] = (_Float16)x[((size_t)b * NN + n0 + row) * DD + d0 + c];
    }
    __syncthreads();
#pragma unroll
    for (int i = 0; i < 4; ++i) {
        int dr = rq + i * 8;
        xT[((size_t)b * DD + d0 + dr) * NN + n0 + c] = tl[c][dr];
    }
}

// ---------------- Kernel C: flash attention ----------------
// 256 blocks (b, q-block of 64). 4 waves x 16 q-rows. KV-step = 32, K and
// V(=xT) tiles staged in LDS shared by the 4 waves. Online softmax with
// defer-max (THR=8). P goes through per-wave LDS for the A-fragment relayout.
__global__ void __launch_bounds__(256)
attn(const _Float16* __restrict__ qh, const _Float16* __restrict__ kh,
     const _Float16* __restrict__ xT, float* __restrict__ out) {
    __shared__ __align__(16) _Float16 Kl[32][264];      // [kv][d], 528B stride
    __shared__ __align__(16) _Float16 Vl[256][40];      // [d][kv], 80B stride
    __shared__ __align__(16) _Float16 Pl[4][16][40];    // per-wave [qrow][kv]
    const int tid = threadIdx.x;
    const int wave = tid >> 6, lane = tid & 63;
    const int g = lane >> 4, l16 = lane & 15;
    const int b = blockIdx.x >> 5;
    const int q0 = (blockIdx.x & 31) * 64 + wave * 16;

    const _Float16* qb = qh + ((size_t)b * NN + q0) * DD;
    const _Float16* kb = kh + (size_t)b * NN * DD;
    const _Float16* vb = xT + (size_t)b * DD * NN;

    half8 qf[8];
#pragma unroll
    for (int c = 0; c < 8; ++c)
        qf[c] = *(const half8*)(qb + (size_t)l16 * DD + c * 32 + g * 8);

    f32x4 O[16];
    f32x4 zero = {0.f, 0.f, 0.f, 0.f};
#pragma unroll
    for (int t = 0; t < 16; ++t) O[t] = zero;
    float m[4] = {-1e30f, -1e30f, -1e30f, -1e30f};
    float l[4] = {0.f, 0.f, 0.f, 0.f};

    for (int kv0 = 0; kv0 < NN; kv0 += 32) {
        __syncthreads();
        {   // stage K tile: 32 rows x 256 d (coalesced 128B chunks)
            const int r = tid >> 3;
            const int ch = (tid & 7) * 8;
            const _Float16* src = kb + (size_t)(kv0 + r) * DD + ch;
#pragma unroll
            for (int j = 0; j < 4; ++j)
                *(half8*)&Kl[r][ch + j * 64] = *(const half8*)(src + j * 64);
        }
        {   // stage V tile: 256 d-rows x 32 kv (quad-per-row for coalescing)
#pragma unroll
            for (int p = 0; p < 4; ++p) {
                int d = p * 64 + (tid >> 2);
                int ch = (tid & 3) * 8;
                *(half8*)&Vl[d][ch] = *(const half8*)(vb + (size_t)d * NN + kv0 + ch);
            }
        }
        __syncthreads();

        // QK^T: two 16-col kv tiles, K=256 over 8 mfma each
        f32x4 s0 = zero, s1 = zero;
#pragma unroll
        for (int c = 0; c < 8; ++c) {
            half8 k0 = *(const half8*)&Kl[l16][c * 32 + g * 8];
            half8 k1 = *(const half8*)&Kl[16 + l16][c * 32 + g * 8];
            s0 = __builtin_amdgcn_mfma_f32_16x16x32_f16(qf[c], k0, s0, 0, 0, 0);
            s1 = __builtin_amdgcn_mfma_f32_16x16x32_f16(qf[c], k1, s1, 0, 0, 0);
        }

        float p0[4], p1[4], tm[4];
#pragma unroll
        for (int r = 0; r < 4; ++r) {
            p0[r] = s0[r] * 0.0625f;
            p1[r] = s1[r] * 0.0625f;
            tm[r] = fmaxf(p0[r], p1[r]);
        }
#pragma unroll
        for (int mask = 1; mask < 16; mask <<= 1) {
#pragma unroll
            for (int r = 0; r < 4; ++r)
                tm[r] = fmaxf(tm[r], __shfl_xor(tm[r], mask));
        }
        bool need = false;
#pragma unroll
        for (int r = 0; r < 4; ++r) need = need || (tm[r] > m[r] + 8.f);
        if (__ballot(need)) {   // rare: rescale O
#pragma unroll
            for (int r = 0; r < 4; ++r) {
                float nm = fmaxf(m[r], tm[r]);
                float al = __expf(m[r] - nm);
                m[r] = nm;
                l[r] *= al;
#pragma unroll
                for (int t = 0; t < 16; ++t) O[t][r] *= al;
            }
        }
        float rs[4];
#pragma unroll
        for (int r = 0; r < 4; ++r) {
            p0[r] = __expf(p0[r] - m[r]);   // bounded by e^8
            p1[r] = __expf(p1[r] - m[r]);
            rs[r] = p0[r] + p1[r];
        }
#pragma unroll
        for (int mask = 1; mask < 16; mask <<= 1) {
#pragma unroll
            for (int r = 0; r < 4; ++r) rs[r] += __shfl_xor(rs[r], mask);
        }
#pragma unroll
        for (int r = 0; r < 4; ++r) l[r] += rs[r];

        // P -> fp16 -> per-wave LDS (sim layout) -> A-fragment layout
#pragma unroll
        for (int r = 0; r < 4; ++r) {
            Pl[wave][g * 4 + r][l16]      = (_Float16)p0[r];
            Pl[wave][g * 4 + r][16 + l16] = (_Float16)p1[r];
        }
        asm volatile("s_waitcnt lgkmcnt(0)" ::: "memory");
        half8 pf = *(const half8*)&Pl[wave][l16][g * 8];
#pragma unroll
        for (int t = 0; t < 16; ++t) {
            half8 vf = *(const half8*)&Vl[t * 16 + l16][g * 8];
            O[t] = __builtin_amdgcn_mfma_f32_16x16x32_f16(pf, vf, O[t], 0, 0, 0);
        }
    }

    float rl[4];
#pragma unroll
    for (int r = 0; r < 4; ++r) rl[r] = 1.0f / l[r];
    float* ob = out + ((size_t)b * NN + q0) * DD;
#pragma unroll
    for (int t = 0; t < 16; ++t) {
#pragma unroll
        for (int r = 0; r < 4; ++r)
            ob[(size_t)(g * 4 + r) * DD + t * 16 + l16] = O[t][r] * rl[r];
    }
}

extern "C" void kernel_launch(void* const* d_in, const int* in_sizes, int n_in,
                              void* d_out, int out_size, void* d_ws, size_t ws_size,
                              hipStream_t stream) {
    const float* x  = (const float*)d_in[0];
    const float* Wq = (const float*)d_in[1];
    const float* Wk = (const float*)d_in[2];
    float* out = (float*)d_out;

    _Float16* qh = (_Float16*)d_ws;                    // 8 MB
    _Float16* kh = qh + (size_t)BB * NN * DD;          // 8 MB
    _Float16* xT = kh + (size_t)BB * NN * DD;          // 8 MB  (24 MB total)

    qk_proj<<<dim3(BB * NN / 64), dim3(256), 0, stream>>>(x, Wq, Wk, qh, kh);
    x_transpose<<<dim3(DD / 32, NN / 32, BB), dim3(256), 0, stream>>>(x, xT);
    attn<<<dim3(BB * NN / 64), dim3(256), 0, stream>>>(qh, kh, xT, out);
}

// Round 2
// 137.796 us; speedup vs baseline: 1.1718x; 1.1718x over previous
//
#include <hip/hip_runtime.h>
#include <hip/hip_bf16.h>

#define BB 8
#define NN 2048
#define DD 256

typedef _Float16 half8 __attribute__((ext_vector_type(8)));
typedef float f32x4 __attribute__((ext_vector_type(4)));

__device__ __forceinline__ half8 cvt8(const float* __restrict__ p) {
    f32x4 a = *(const f32x4*)p;
    f32x4 b = *(const f32x4*)(p + 4);
    half8 h;
    h[0] = (_Float16)a[0]; h[1] = (_Float16)a[1];
    h[2] = (_Float16)a[2]; h[3] = (_Float16)a[3];
    h[4] = (_Float16)b[0]; h[5] = (_Float16)b[1];
    h[6] = (_Float16)b[2]; h[7] = (_Float16)b[3];
    return h;
}

// ---------------- Kernel A: qh = (x@Wq^T)*scale, kh = x@Wk^T (fp16 out) -------
// Grid 512: blockIdx = rowblk*2 + thalf. 4 waves x 16 token-rows, 8 col-tiles.
__global__ void __launch_bounds__(256)
qk_proj(const float* __restrict__ x, const float* __restrict__ Wq,
        const float* __restrict__ Wk, _Float16* __restrict__ qh,
        _Float16* __restrict__ kh) {
    __shared__ __align__(16) _Float16 Wql[16][264];
    __shared__ __align__(16) _Float16 Wkl[16][264];
    const int tid = threadIdx.x;
    const int wave = tid >> 6, lane = tid & 63;
    const int g = lane >> 4, l16 = lane & 15;
    const int rowblk = blockIdx.x >> 1, thalf = blockIdx.x & 1;
    const size_t r0 = ((size_t)rowblk * 4 + wave) * 16;

    half8 xa[8];
#pragma unroll
    for (int c = 0; c < 8; ++c)
        xa[c] = cvt8(x + (r0 + l16) * DD + c * 32 + g * 8);

    for (int i = 0; i < 8; ++i) {
        const int t = thalf * 8 + i;
        __syncthreads();
        {
            const int sel = tid >> 7;
            const int tt  = tid & 127;
            const int row = tt >> 3;
            const int col = (tt & 7) * 32;
            const float* src = (sel ? Wk : Wq) + (size_t)(t * 16 + row) * DD + col;
            _Float16* dst = sel ? &Wkl[row][col] : &Wql[row][col];
#pragma unroll
            for (int j = 0; j < 4; ++j)
                *(half8*)(dst + j * 8) = cvt8(src + j * 8);
        }
        __syncthreads();
        f32x4 aq = {0.f, 0.f, 0.f, 0.f}, ak = {0.f, 0.f, 0.f, 0.f};
#pragma unroll
        for (int c = 0; c < 8; ++c) {
            half8 bq = *(const half8*)&Wql[l16][c * 32 + g * 8];
            half8 bk = *(const half8*)&Wkl[l16][c * 32 + g * 8];
            aq = __builtin_amdgcn_mfma_f32_16x16x32_f16(xa[c], bq, aq, 0, 0, 0);
            ak = __builtin_amdgcn_mfma_f32_16x16x32_f16(xa[c], bk, ak, 0, 0, 0);
        }
#pragma unroll
        for (int r = 0; r < 4; ++r) {
            size_t row = r0 + g * 4 + r;
            qh[row * DD + t * 16 + l16] = (_Float16)(aq[r] * 0.0625f);  // fold 1/sqrt(d)
            kh[row * DD + t * 16 + l16] = (_Float16)ak[r];
        }
    }
}

// ---------------- Kernel B: xT[b][d][n] = (fp16) x[b][n][d] ----------------
__global__ void __launch_bounds__(256)
x_transpose(const float* __restrict__ x, _Float16* __restrict__ xT) {
    __shared__ _Float16 tl[32][33];
    const int b = blockIdx.z;
    const int n0 = blockIdx.y * 32, d0 = blockIdx.x * 32;
    const int c = threadIdx.x & 31, rq = threadIdx.x >> 5;
#pragma unroll
    for (int i = 0; i < 4; ++i) {
        int row = rq + i * 8;
        tl[row][c] = (_Float16)x[((size_t)b * NN + n0 + row) * DD + d0 + c];
    }
    __syncthreads();
#pragma unroll
    for (int i = 0; i < 4; ++i) {
        int dr = rq + i * 8;
        xT[((size_t)b * DD + d0 + dr) * NN + n0 + c] = tl[c][dr];
    }
}

// ---------------- Kernel C: flash attention with KV-split ----------------
// Grid = BB * (NN/64) * S, bid = (qb*S + s)*8 + b (batch -> XCD affinity).
// 4 waves x 16 q-rows. KV-step 32. S>1: write unnormalized O + (m,l) partials.
__global__ void __launch_bounds__(256)
attn(const _Float16* __restrict__ qh, const _Float16* __restrict__ kh,
     const _Float16* __restrict__ xT, float* __restrict__ out,
     float* __restrict__ Op, float* __restrict__ ml, int lgS) {
    __shared__ __align__(16) _Float16 Kl[32][264];
    __shared__ __align__(16) _Float16 Vl[256][40];
    __shared__ __align__(16) _Float16 Pl[4][16][40];
    const int tid = threadIdx.x;
    const int wave = tid >> 6, lane = tid & 63;
    const int g = lane >> 4, l16 = lane & 15;
    const int S = 1 << lgS;
    const int b = blockIdx.x & 7;
    const int tt = blockIdx.x >> 3;
    const int s = tt & (S - 1);
    const int qb = tt >> lgS;
    const int q0 = qb * 64 + wave * 16;
    const int kvlen = NN >> lgS;
    const int kv_begin = s * kvlen;

    const _Float16* qb_p = qh + ((size_t)b * NN + q0) * DD;
    const _Float16* kb = kh + (size_t)b * NN * DD;
    const _Float16* vb = xT + (size_t)b * DD * NN;

    half8 qf[8];
#pragma unroll
    for (int c = 0; c < 8; ++c)
        qf[c] = *(const half8*)(qb_p + (size_t)l16 * DD + c * 32 + g * 8);

    f32x4 O[16];
    f32x4 zero = {0.f, 0.f, 0.f, 0.f};
#pragma unroll
    for (int t = 0; t < 16; ++t) O[t] = zero;
    float m[4] = {-1e30f, -1e30f, -1e30f, -1e30f};
    float l[4] = {0.f, 0.f, 0.f, 0.f};

    for (int kv0 = kv_begin; kv0 < kv_begin + kvlen; kv0 += 32) {
        __syncthreads();
        {   // stage K tile: 32 rows x 256 d
            const int r = tid >> 3;
            const int ch = (tid & 7) * 8;
            const _Float16* src = kb + (size_t)(kv0 + r) * DD + ch;
#pragma unroll
            for (int j = 0; j < 4; ++j)
                *(half8*)&Kl[r][ch + j * 64] = *(const half8*)(src + j * 64);
        }
        {   // stage V tile: 256 d-rows x 32 kv
#pragma unroll
            for (int p = 0; p < 4; ++p) {
                int d = p * 64 + (tid >> 2);
                int ch = (tid & 3) * 8;
                *(half8*)&Vl[d][ch] = *(const half8*)(vb + (size_t)d * NN + kv0 + ch);
            }
        }
        __syncthreads();

        f32x4 s0 = zero, s1 = zero;
#pragma unroll
        for (int c = 0; c < 8; ++c) {
            half8 k0 = *(const half8*)&Kl[l16][c * 32 + g * 8];
            half8 k1 = *(const half8*)&Kl[16 + l16][c * 32 + g * 8];
            s0 = __builtin_amdgcn_mfma_f32_16x16x32_f16(qf[c], k0, s0, 0, 0, 0);
            s1 = __builtin_amdgcn_mfma_f32_16x16x32_f16(qf[c], k1, s1, 0, 0, 0);
        }

        float p0[4], p1[4], tm[4];
#pragma unroll
        for (int r = 0; r < 4; ++r) {
            p0[r] = s0[r];          // scale already folded into qh
            p1[r] = s1[r];
            tm[r] = fmaxf(p0[r], p1[r]);
        }
#pragma unroll
        for (int mask = 1; mask < 16; mask <<= 1) {
#pragma unroll
            for (int r = 0; r < 4; ++r)
                tm[r] = fmaxf(tm[r], __shfl_xor(tm[r], mask));
        }
        bool need = false;
#pragma unroll
        for (int r = 0; r < 4; ++r) need = need || (tm[r] > m[r] + 8.f);
        if (__ballot(need)) {
#pragma unroll
            for (int r = 0; r < 4; ++r) {
                float nm = fmaxf(m[r], tm[r]);
                float al = __expf(m[r] - nm);
                m[r] = nm;
                l[r] *= al;
#pragma unroll
                for (int t = 0; t < 16; ++t) O[t][r] *= al;
            }
        }
        float rs[4];
#pragma unroll
        for (int r = 0; r < 4; ++r) {
            p0[r] = __expf(p0[r] - m[r]);
            p1[r] = __expf(p1[r] - m[r]);
            rs[r] = p0[r] + p1[r];
        }
#pragma unroll
        for (int mask = 1; mask < 16; mask <<= 1) {
#pragma unroll
            for (int r = 0; r < 4; ++r) rs[r] += __shfl_xor(rs[r], mask);
        }
#pragma unroll
        for (int r = 0; r < 4; ++r) l[r] += rs[r];

#pragma unroll
        for (int r = 0; r < 4; ++r) {
            Pl[wave][g * 4 + r][l16]      = (_Float16)p0[r];
            Pl[wave][g * 4 + r][16 + l16] = (_Float16)p1[r];
        }
        asm volatile("s_waitcnt lgkmcnt(0)" ::: "memory");
        half8 pf = *(const half8*)&Pl[wave][l16][g * 8];
#pragma unroll
        for (int t = 0; t < 16; ++t) {
            half8 vf = *(const half8*)&Vl[t * 16 + l16][g * 8];
            O[t] = __builtin_amdgcn_mfma_f32_16x16x32_f16(pf, vf, O[t], 0, 0, 0);
        }
    }

    if (lgS == 0) {
        float rl[4];
#pragma unroll
        for (int r = 0; r < 4; ++r) rl[r] = 1.0f / l[r];
        float* ob = out + ((size_t)b * NN + q0) * DD;
#pragma unroll
        for (int t = 0; t < 16; ++t) {
#pragma unroll
            for (int r = 0; r < 4; ++r)
                ob[(size_t)(g * 4 + r) * DD + t * 16 + l16] = O[t][r] * rl[r];
        }
    } else {
        float* ob = Op + (((size_t)s * BB + b) * NN + q0) * DD;
#pragma unroll
        for (int t = 0; t < 16; ++t) {
#pragma unroll
            for (int r = 0; r < 4; ++r)
                ob[(size_t)(g * 4 + r) * DD + t * 16 + l16] = O[t][r];
        }
        if (l16 == 0) {
            float* mlp = ml + (((size_t)s * BB + b) * NN + q0) * 2;
#pragma unroll
            for (int r = 0; r < 4; ++r) {
                mlp[(g * 4 + r) * 2]     = m[r];
                mlp[(g * 4 + r) * 2 + 1] = l[r];
            }
        }
    }
}

// ---------------- Kernel D: combine KV-split partials ----------------
__global__ void __launch_bounds__(256)
combine(const float* __restrict__ Op, const float* __restrict__ ml,
        float* __restrict__ out, int S) {
    const int row = blockIdx.x * 4 + (threadIdx.x >> 6);
    const int col = (threadIdx.x & 63) * 4;
    float M = -1e30f;
    for (int s = 0; s < S; ++s)
        M = fmaxf(M, ml[((size_t)s * BB * NN + row) * 2]);
    float denom = 0.f;
    f32x4 acc = {0.f, 0.f, 0.f, 0.f};
    for (int s = 0; s < S; ++s) {
        const float* mlp = ml + ((size_t)s * BB * NN + row) * 2;
        float w = __expf(mlp[0] - M);
        denom += w * mlp[1];
        f32x4 o = *(const f32x4*)(Op + ((size_t)s * BB * NN + row) * DD + col);
        acc[0] += w * o[0]; acc[1] += w * o[1];
        acc[2] += w * o[2]; acc[3] += w * o[3];
    }
    float inv = 1.0f / denom;
    f32x4 res = {acc[0] * inv, acc[1] * inv, acc[2] * inv, acc[3] * inv};
    *(f32x4*)(out + (size_t)row * DD + col) = res;
}

extern "C" void kernel_launch(void* const* d_in, const int* in_sizes, int n_in,
                              void* d_out, int out_size, void* d_ws, size_t ws_size,
                              hipStream_t stream) {
    const float* x  = (const float*)d_in[0];
    const float* Wq = (const float*)d_in[1];
    const float* Wk = (const float*)d_in[2];
    float* out = (float*)d_out;

    const size_t NTOK = (size_t)BB * NN;
    const size_t HBUF = NTOK * DD * sizeof(_Float16);  // 8.4 MB
    _Float16* qh = (_Float16*)d_ws;
    _Float16* kh = qh + NTOK * DD;
    _Float16* xT = kh + NTOK * DD;
    const size_t base = 3 * HBUF;                      // 25.2 MB
    const size_t OSZ  = NTOK * DD * sizeof(float);     // 16.8 MB / split
    const size_t MLSZ = NTOK * 2 * sizeof(float);      // 128 KB / split

    int lgS = 0;
    if (ws_size >= base + 4 * (OSZ + MLSZ)) lgS = 2;
    else if (ws_size >= base + 2 * (OSZ + MLSZ)) lgS = 1;
    const int S = 1 << lgS;

    float* Op = (float*)((char*)d_ws + base);
    float* ml = (float*)((char*)d_ws + base + (size_t)S * OSZ);

    qk_proj<<<dim3(BB * NN / 64 * 2), dim3(256), 0, stream>>>(x, Wq, Wk, qh, kh);
    x_transpose<<<dim3(DD / 32, NN / 32, BB), dim3(256), 0, stream>>>(x, xT);
    attn<<<dim3(BB * (NN / 64) * S), dim3(256), 0, stream>>>(qh, kh, xT, out, Op, ml, lgS);
    if (S > 1)
        combine<<<dim3(BB * NN / 4), dim3(256), 0, stream>>>(Op, ml, out, S);
}